// Round 1
// baseline (741.019 us; speedup 1.0000x reference)
//
#include <hip/hip_runtime.h>

#define N_ROWS 32768
#define DIM 256
#define KCENT 2048
#define NSPLIT 4
#define CPG (KCENT / NSPLIT)   // 512 centroids per group
#define BM 64
#define BN 64
#define BKK 32
#define LSTR 36                // BK + 4 pad, keeps 16B alignment for float4 LDS ops

// workspace layout (float offsets)
#define WS_SUMSQ  0            // 32768 floats
#define WS_CSQ    32768        // 2048
#define WS_COUNTS 34816        // 2048
#define WS_IDX    36864        // 32768 (int)
#define WS_PVAL   69632        // 4*32768
#define WS_PIDX   200704       // 4*32768 (int)

// output layout (float offsets), ref return order:
// (quantized, quantization_loss, nn_idx, codebook_values, new_counts)
#define OUT_Q    0
#define OUT_LOSS 8388608
#define OUT_IDX  16777216
#define OUT_CB   16809984
#define OUT_CNT  17334272

__global__ __launch_bounds__(256) void vq_precompute(
    const float* __restrict__ X, const float* __restrict__ C,
    float* __restrict__ sumsq, float* __restrict__ csq,
    float* __restrict__ counts)
{
  int bid = blockIdx.x, tid = threadIdx.x;
  int wave = tid >> 6, lane = tid & 63;
  if (bid < 8192) {
    int row = bid * 4 + wave;
    float4 v = *(const float4*)(X + (size_t)row * DIM + lane * 4);
    float s = v.x * v.x + v.y * v.y + v.z * v.z + v.w * v.w;
#pragma unroll
    for (int off = 32; off > 0; off >>= 1) s += __shfl_down(s, off);
    if (lane == 0) sumsq[row] = s;
  } else if (bid < 8704) {
    int cent = (bid - 8192) * 4 + wave;
    float4 v = *(const float4*)(C + (size_t)cent * DIM + lane * 4);
    float s = v.x * v.x + v.y * v.y + v.z * v.z + v.w * v.w;
#pragma unroll
    for (int off = 32; off > 0; off >>= 1) s += __shfl_down(s, off);
    if (lane == 0) csq[cent] = s;
  } else {
    for (int i = tid; i < KCENT; i += 256) counts[i] = 0.0f;
  }
}

// Fused GEMM+argmin: block = 64 rows x 512 centroids (one of 4 groups).
// Thread (ty,tx) in 16x16 grid owns rows {ty+16m} and (per tile) cents {c0+tx+16n}
// -> swizzled ownership keeps ds_read_b128 conflict-free with LSTR=36.
__global__ __launch_bounds__(256) void vq_argmin(
    const float* __restrict__ X, const float* __restrict__ C,
    const float* __restrict__ sumsq, const float* __restrict__ csq,
    float* __restrict__ pval, int* __restrict__ pidx)
{
  __shared__ __align__(16) float sA[BM * LSTR];
  __shared__ __align__(16) float sB[BN * LSTR];

  const int tid = threadIdx.x;
  const int tx = tid & 15, ty = tid >> 4;
  const int row0 = blockIdx.x * BM;
  const int g = blockIdx.y;
  const int cg0 = g * CPG;

  float sx[4];
#pragma unroll
  for (int m = 0; m < 4; ++m) sx[m] = sumsq[row0 + ty + 16 * m];

  float rmin[4];
  int ridx[4];
#pragma unroll
  for (int m = 0; m < 4; ++m) { rmin[m] = 3.4e38f; ridx[m] = 0; }

  // staging indices (invariant over loops)
  const int r_a = tid >> 3;           // 0..31 (thread covers id=tid and id=tid+256)
  const int c4_a = (tid & 7) << 2;    // 0,4,...,28

  for (int t = 0; t < CPG / BN; ++t) {
    const int c0 = cg0 + t * BN;
    float acc[4][4];
#pragma unroll
    for (int m = 0; m < 4; ++m)
#pragma unroll
      for (int n = 0; n < 4; ++n) acc[m][n] = 0.0f;

    for (int kc = 0; kc < DIM; kc += BKK) {
      __syncthreads();  // protect previous tile-chunk reads before overwrite
#pragma unroll
      for (int s = 0; s < 2; ++s) {
        int id = tid + s * 256;
        int r = id >> 3;
        int c4 = (id & 7) << 2;
        float4 va = *(const float4*)(X + (size_t)(row0 + r) * DIM + kc + c4);
        *(float4*)&sA[r * LSTR + c4] = va;
        float4 vb = *(const float4*)(C + (size_t)(c0 + r) * DIM + kc + c4);
        *(float4*)&sB[r * LSTR + c4] = vb;
      }
      __syncthreads();
#pragma unroll
      for (int j = 0; j < BKK; j += 4) {
        float4 a[4], b[4];
#pragma unroll
        for (int m = 0; m < 4; ++m)
          a[m] = *(const float4*)&sA[(ty + 16 * m) * LSTR + j];
#pragma unroll
        for (int n = 0; n < 4; ++n)
          b[n] = *(const float4*)&sB[(tx + 16 * n) * LSTR + j];
#pragma unroll
        for (int m = 0; m < 4; ++m)
#pragma unroll
          for (int n = 0; n < 4; ++n)
            acc[m][n] += a[m].x * b[n].x + a[m].y * b[n].y +
                         a[m].z * b[n].z + a[m].w * b[n].w;
      }
    }

    // tile epilogue: distances, running argmin (cent indices ascending in n,t)
#pragma unroll
    for (int m = 0; m < 4; ++m) {
#pragma unroll
      for (int n = 0; n < 4; ++n) {
        int cent = c0 + tx + 16 * n;
        float d = (sx[m] - 2.0f * acc[m][n]) + csq[cent];  // ref fp32 op order
        if (d < rmin[m]) { rmin[m] = d; ridx[m] = cent; }
      }
    }
  }

  // cross-thread reduce over the 16 tx lanes of each row (lex tie-break: lowest idx)
  __syncthreads();
  float* rv = sA;          // 64*16 floats
  int* ri = (int*)sB;
#pragma unroll
  for (int m = 0; m < 4; ++m) {
    rv[(ty + 16 * m) * 16 + tx] = rmin[m];
    ri[(ty + 16 * m) * 16 + tx] = ridx[m];
  }
  __syncthreads();
  if (tid < 64) {
    float bv = rv[tid * 16];
    int bi = ri[tid * 16];
#pragma unroll
    for (int t2 = 1; t2 < 16; ++t2) {
      float v = rv[tid * 16 + t2];
      int i = ri[tid * 16 + t2];
      if (v < bv || (v == bv && i < bi)) { bv = v; bi = i; }
    }
    pval[g * N_ROWS + row0 + tid] = bv;
    pidx[g * N_ROWS + row0 + tid] = bi;
  }
}

__global__ __launch_bounds__(256) void vq_reduce(
    const float* __restrict__ pval, const int* __restrict__ pidx,
    float* __restrict__ out_idx, int* __restrict__ idxbuf,
    float* __restrict__ counts)
{
  int r = blockIdx.x * 256 + threadIdx.x;
  float bv = pval[r];
  int bi = pidx[r];
#pragma unroll
  for (int g = 1; g < NSPLIT; ++g) {
    float v = pval[g * N_ROWS + r];
    int i = pidx[g * N_ROWS + r];
    if (v < bv || (v == bv && i < bi)) { bv = v; bi = i; }
  }
  out_idx[r] = (float)bi;
  idxbuf[r] = bi;
  atomicAdd(&counts[bi], 1.0f);
}

__global__ __launch_bounds__(256) void vq_outputs(
    const float* __restrict__ X, const float* __restrict__ C,
    const float* __restrict__ cc, const int* __restrict__ idxbuf,
    const float* __restrict__ counts, float* __restrict__ out)
{
  int bid = blockIdx.x, tid = threadIdx.x;
  if (bid < 8192) {
    int f4 = bid * 256 + tid;          // float4 index into [N_ROWS*DIM)
    int row = f4 >> 6;                 // 64 float4 per row
    int col = (f4 & 63) << 2;
    int idx = idxbuf[row];
    float4 x = *(const float4*)(X + (size_t)row * DIM + col);
    float4 q = *(const float4*)(C + (size_t)idx * DIM + col);
    float4 o, l;
    // straight-through: x + (q - x); loss: s + 0.25*s with s=(q-x)^2 (ref op order)
    float dx = q.x - x.x, dy = q.y - x.y, dz = q.z - x.z, dw = q.w - x.w;
    o.x = x.x + dx; o.y = x.y + dy; o.z = x.z + dz; o.w = x.w + dw;
    float s0 = dx * dx, s1 = dy * dy, s2 = dz * dz, s3 = dw * dw;
    l.x = s0 + 0.25f * s0; l.y = s1 + 0.25f * s1;
    l.z = s2 + 0.25f * s2; l.w = s3 + 0.25f * s3;
    *(float4*)(out + OUT_Q + (size_t)f4 * 4) = o;
    *(float4*)(out + OUT_LOSS + (size_t)f4 * 4) = l;
  } else if (bid < 8704) {
    int f4 = (bid - 8192) * 256 + tid;  // codebook copy: 131072 float4
    float4 v = *(const float4*)(C + (size_t)f4 * 4);
    *(float4*)(out + OUT_CB + (size_t)f4 * 4) = v;
  } else {
    for (int i = tid; i < KCENT; i += 256)
      out[OUT_CNT + i] = 0.99f * cc[i] + 0.01f * counts[i];
  }
}

extern "C" void kernel_launch(void* const* d_in, const int* in_sizes, int n_in,
                              void* d_out, int out_size, void* d_ws, size_t ws_size,
                              hipStream_t stream) {
  const float* X = (const float*)d_in[0];
  const float* C = (const float*)d_in[1];
  const float* cc = (const float*)d_in[2];
  float* out = (float*)d_out;
  float* ws = (float*)d_ws;

  float* sumsq = ws + WS_SUMSQ;
  float* csq = ws + WS_CSQ;
  float* counts = ws + WS_COUNTS;
  int* idxbuf = (int*)(ws + WS_IDX);
  float* pval = ws + WS_PVAL;
  int* pidx = (int*)(ws + WS_PIDX);

  vq_precompute<<<8705, 256, 0, stream>>>(X, C, sumsq, csq, counts);
  vq_argmin<<<dim3(N_ROWS / BM, NSPLIT), 256, 0, stream>>>(X, C, sumsq, csq, pval, pidx);
  vq_reduce<<<N_ROWS / 256, 256, 0, stream>>>(pval, pidx, out + OUT_IDX, idxbuf, counts);
  vq_outputs<<<8705, 256, 0, stream>>>(X, C, cc, idxbuf, counts, out);
}

// Round 2
// 456.286 us; speedup vs baseline: 1.6240x; 1.6240x over previous
//
#include <hip/hip_runtime.h>
#include <math.h>

typedef unsigned short ushort_t;

#define N_ROWS 32768
#define DIM 256
#define KCENT 2048

// ---------------- fp32 fallback path constants (round-1 kernel) -------------
#define NSPLIT 4
#define CPG (KCENT / NSPLIT)
#define BM 64
#define BN 64
#define BKK 32
#define LSTR 36

#define WS_SUMSQ  0
#define WS_CSQ    32768
#define WS_COUNTS 34816
#define WS_IDX    36864
#define WS_PVAL   69632
#define WS_PIDX   200704

// ---------------- output layout (float offsets) -----------------------------
#define OUT_Q    0
#define OUT_LOSS 8388608
#define OUT_IDX  16777216
#define OUT_CB   16809984
#define OUT_CNT  17334272

// ---------------- MFMA path workspace (byte offsets) ------------------------
#define WB_A2     0UL            // 32768 x 512 bf16 = [x_hi | x_lo]
#define WB_B3     33554432UL     // 2048 x 768 bf16 = [c_hi | c_hi | c_lo]
#define WB_PV1    36700160UL     // 32 x 32768 f32
#define WB_PI1    40894464UL     // 32 x 32768 i32
#define WB_PV2    45088768UL     // 32 x 32768 f32
#define WB_SUMSQ  49283072UL     // 32768 f32 (exact ||x||^2)
#define WB_XLO    49414144UL     // 32768 f32 (||x_lo||)
#define WB_XR     49545216UL     // 32768 f32 (||r_x||)
#define WB_CSQ    49676288UL     // 2048 f32 (exact ||c||^2)
#define WB_COUNTS 49684480UL     // 2048 f32
#define WB_IDXBUF 49692672UL     // 32768 i32
#define WB_RLIST  49823744UL     // 32768 i32
#define WB_MISC   49954816UL     // rcnt(i32) @ +0, maxes(u32[3]) @ +8
#define WS_NEED   49955072UL

// ---------------- helpers ---------------------------------------------------
__device__ __forceinline__ ushort_t f2bf(float f) {
  unsigned u = __float_as_uint(f);
  unsigned r = (u + 0x7fffu + ((u >> 16) & 1u)) >> 16;   // RNE
  return (ushort_t)r;
}
__device__ __forceinline__ float bf2f(ushort_t h) {
  return __uint_as_float(((unsigned)h) << 16);
}

#define ASYNC_COPY16(gptr, lptr)                                               \
  __builtin_amdgcn_global_load_lds(                                            \
      (const __attribute__((address_space(1))) void*)(gptr),                   \
      (__attribute__((address_space(3))) void*)(lptr), 16, 0, 0)

typedef __bf16 bf16x8 __attribute__((ext_vector_type(8)));
typedef float f32x4 __attribute__((ext_vector_type(4)));

// merge candidate (d, ci) into (m1,i1,m2); lowest-index tie-break on m1
__device__ __forceinline__ void merge1(float d, int ci, float& m1, int& i1, float& m2) {
  if (d < m1 || (d == m1 && ci < i1)) { m2 = m1; m1 = d; i1 = ci; }
  else { m2 = fminf(m2, d); }
}
__device__ __forceinline__ void merge3(float& m1, int& i1, float& m2,
                                       float om1, int oi1, float om2) {
  float loser;
  if (om1 < m1 || (om1 == m1 && oi1 < i1)) { loser = m1; m1 = om1; i1 = oi1; }
  else { loser = om1; }
  m2 = fminf(fminf(m2, om2), loser);
}

// ============================================================================
//                               MFMA PATH
// ============================================================================

__global__ __launch_bounds__(256) void vq_init(float* counts, int* rcnt, unsigned* maxes) {
  int tid = threadIdx.x;
  for (int i = tid; i < KCENT; i += 256) counts[i] = 0.0f;
  if (tid == 0) { *rcnt = 0; maxes[0] = 0u; maxes[1] = 0u; maxes[2] = 0u; }
}

// split X into bf16 hi/lo + per-row norms; one wave per row
__global__ __launch_bounds__(256) void vq_conv_x(
    const float* __restrict__ X, ushort_t* __restrict__ A2,
    float* __restrict__ sumsq, float* __restrict__ xlo_n, float* __restrict__ xr_n)
{
  int row = blockIdx.x * 4 + (threadIdx.x >> 6);
  int lane = threadIdx.x & 63;
  float4 v = *(const float4*)(X + (size_t)row * DIM + lane * 4);
  float xv[4] = {v.x, v.y, v.z, v.w};
  ushort_t hb[4], lb[4];
  float s2 = 0.f, l2 = 0.f, r2 = 0.f;
#pragma unroll
  for (int e = 0; e < 4; ++e) {
    float x = xv[e];
    hb[e] = f2bf(x);
    float hf = bf2f(hb[e]);
    float lrem = x - hf;
    lb[e] = f2bf(lrem);
    float lf = bf2f(lb[e]);
    float r = lrem - lf;
    s2 += x * x; l2 += lf * lf; r2 += r * r;
  }
  ushort4 hv = make_ushort4(hb[0], hb[1], hb[2], hb[3]);
  ushort4 lv = make_ushort4(lb[0], lb[1], lb[2], lb[3]);
  *(ushort4*)(A2 + (size_t)row * 512 + lane * 4) = hv;
  *(ushort4*)(A2 + (size_t)row * 512 + 256 + lane * 4) = lv;
#pragma unroll
  for (int off = 32; off > 0; off >>= 1) {
    s2 += __shfl_down(s2, off);
    l2 += __shfl_down(l2, off);
    r2 += __shfl_down(r2, off);
  }
  if (lane == 0) { sumsq[row] = s2; xlo_n[row] = sqrtf(l2); xr_n[row] = sqrtf(r2); }
}

// split C into [hi|hi|lo] + per-cent norms + global maxes; one wave per centroid
__global__ __launch_bounds__(256) void vq_conv_c(
    const float* __restrict__ C, ushort_t* __restrict__ B3,
    float* __restrict__ csq, unsigned* __restrict__ maxes)
{
  int c = blockIdx.x * 4 + (threadIdx.x >> 6);
  int lane = threadIdx.x & 63;
  float4 v = *(const float4*)(C + (size_t)c * DIM + lane * 4);
  float xv[4] = {v.x, v.y, v.z, v.w};
  ushort_t hb[4], lb[4];
  float s2 = 0.f, l2 = 0.f, r2 = 0.f;
#pragma unroll
  for (int e = 0; e < 4; ++e) {
    float x = xv[e];
    hb[e] = f2bf(x);
    float hf = bf2f(hb[e]);
    float lrem = x - hf;
    lb[e] = f2bf(lrem);
    float lf = bf2f(lb[e]);
    float r = lrem - lf;
    s2 += x * x; l2 += lf * lf; r2 += r * r;
  }
  ushort4 hv = make_ushort4(hb[0], hb[1], hb[2], hb[3]);
  ushort4 lv = make_ushort4(lb[0], lb[1], lb[2], lb[3]);
  *(ushort4*)(B3 + (size_t)c * 768 + lane * 4) = hv;
  *(ushort4*)(B3 + (size_t)c * 768 + 256 + lane * 4) = hv;
  *(ushort4*)(B3 + (size_t)c * 768 + 512 + lane * 4) = lv;
#pragma unroll
  for (int off = 32; off > 0; off >>= 1) {
    s2 += __shfl_down(s2, off);
    l2 += __shfl_down(l2, off);
    r2 += __shfl_down(r2, off);
  }
  if (lane == 0) {
    csq[c] = s2;
    float cn = sqrtf(s2), clo = sqrtf(l2), cr = sqrtf(r2);
    atomicMax(&maxes[0], __float_as_uint(clo + cr));  // max ||c - c_hi||
    atomicMax(&maxes[1], __float_as_uint(cn));        // max ||c||
    atomicMax(&maxes[2], __float_as_uint(cr));        // max ||r_c||
  }
}

// MFMA GEMM (virtual K=768) + fused per-64-cent argmin(+second-min) epilogue.
// Block: 128 rows x 128 cents, 4 waves of 64x64, 16x16x32 bf16 MFMA.
#define GBM 128
#define GBN 128
#define GBK 32
__global__ __launch_bounds__(256) void vq_mfma(
    const ushort_t* __restrict__ A2, const ushort_t* __restrict__ B3,
    const float* __restrict__ sumsq, const float* __restrict__ csq,
    float* __restrict__ pv1, int* __restrict__ pi1, float* __restrict__ pv2)
{
  __shared__ __align__(16) ushort_t sA[GBM * GBK];
  __shared__ __align__(16) ushort_t sB[GBN * GBK];

  const int tid = threadIdx.x;
  const int wave = tid >> 6, lane = tid & 63;
  const int lc = lane & 15, quad = lane >> 4;
  const int wm = wave >> 1, wn = wave & 1;
  const int row0 = blockIdx.y * GBM;
  const int cb0 = blockIdx.x * GBN;

  f32x4 acc[4][4] = {};

  // staging geometry: wave w covers tile rows [w*32, w*32+32), instr j covers 16 rows
  const int st_row = wave * 32 + (lane >> 2);   // + j*16
  const int st_ko = (lane & 3) * 8;
  const ushort_t* gA = A2 + (size_t)(row0 + st_row) * 512 + st_ko;
  const ushort_t* gB = B3 + (size_t)(cb0 + st_row) * 768 + st_ko;

  for (int kt = 0; kt < 24; ++kt) {
    const int a_k0 = (kt < 16) ? kt * 32 : (kt - 16) * 32;
    const int b_k0 = kt * 32;
    __syncthreads();
#pragma unroll
    for (int j = 0; j < 2; ++j) {
      ASYNC_COPY16(gA + (size_t)(j * 16) * 512 + a_k0, &sA[(wave * 32 + j * 16) * GBK]);
      ASYNC_COPY16(gB + (size_t)(j * 16) * 768 + b_k0, &sB[(wave * 32 + j * 16) * GBK]);
    }
    __syncthreads();
    bf16x8 fa[4], fb[4];
#pragma unroll
    for (int i = 0; i < 4; ++i)
      fa[i] = *(const bf16x8*)&sA[(wm * 64 + i * 16 + lc) * GBK + quad * 8];
#pragma unroll
    for (int j = 0; j < 4; ++j)
      fb[j] = *(const bf16x8*)&sB[(wn * 64 + j * 16 + lc) * GBK + quad * 8];
#pragma unroll
    for (int i = 0; i < 4; ++i)
#pragma unroll
      for (int j = 0; j < 4; ++j)
        acc[i][j] = __builtin_amdgcn_mfma_f32_16x16x32_bf16(fa[i], fb[j], acc[i][j], 0, 0, 0);
  }

  // epilogue: distances + (m1,i1,m2) per row over this wave's 64 cents
  float cs[4];
#pragma unroll
  for (int j = 0; j < 4; ++j) cs[j] = csq[cb0 + wn * 64 + j * 16 + lc];
  const int cg = blockIdx.x * 2 + wn;   // 64-cent group index (ascending in cent)

#pragma unroll
  for (int i = 0; i < 4; ++i) {
#pragma unroll
    for (int r = 0; r < 4; ++r) {
      const int row = row0 + wm * 64 + i * 16 + quad * 4 + r;
      const float sx = sumsq[row];
      float m1 = 3.4e38f, m2 = 3.4e38f;
      int i1 = 0;
#pragma unroll
      for (int j = 0; j < 4; ++j) {
        float d = (sx - 2.0f * acc[i][j][r]) + cs[j];
        merge1(d, cb0 + wn * 64 + j * 16 + lc, m1, i1, m2);
      }
#pragma unroll
      for (int off = 1; off < 16; off <<= 1) {
        float om1 = __shfl_xor(m1, off);
        int oi1 = __shfl_xor(i1, off);
        float om2 = __shfl_xor(m2, off);
        merge3(m1, i1, m2, om1, oi1, om2);
      }
      if (lc == 0) {
        pv1[cg * N_ROWS + row] = m1;
        pi1[cg * N_ROWS + row] = i1;
        pv2[cg * N_ROWS + row] = m2;
      }
    }
  }
}

// merge 32 col-groups/row; certify via window; flag uncertified rows
__global__ __launch_bounds__(256) void vq_flagreduce(
    const float* __restrict__ pv1, const int* __restrict__ pi1,
    const float* __restrict__ pv2,
    const float* __restrict__ sumsq, const float* __restrict__ xlo_n,
    const float* __restrict__ xr_n, const unsigned* __restrict__ maxes,
    float* __restrict__ out_idx, int* __restrict__ idxbuf,
    float* __restrict__ counts, int* __restrict__ rcnt, int* __restrict__ rlist)
{
  int r = blockIdx.x * 256 + threadIdx.x;
  float m1 = pv1[r]; int i1 = pi1[r]; float m2 = pv2[r];
  for (int g = 1; g < 32; ++g) {
    merge3(m1, i1, m2, pv1[g * N_ROWS + r], pi1[g * N_ROWS + r], pv2[g * N_ROWS + r]);
  }
  float MA = __uint_as_float(maxes[0]);   // max ||c - c_hi||
  float MB = __uint_as_float(maxes[1]);   // max ||c||
  float MC = __uint_as_float(maxes[2]);   // max ||r_c||
  float xn = sqrtf(sumsq[r]);
  float W = 2.0f * (xlo_n[r] * MA + xr_n[r] * MB + (xn + xlo_n[r]) * MC) + 4e-4f;
  out_idx[r] = (float)i1;
  idxbuf[r] = i1;
  if (m2 - m1 >= W) {
    atomicAdd(&counts[i1], 1.0f);
  } else {
    int p = atomicAdd(rcnt, 1);
    rlist[p] = r;
  }
}

// exact fp32 re-solve for flagged rows (one block per list entry, strided)
__global__ __launch_bounds__(256) void vq_rescue(
    const float* __restrict__ X, const float* __restrict__ C,
    const float* __restrict__ sumsq, const float* __restrict__ csq,
    const int* __restrict__ rcnt, const int* __restrict__ rlist,
    float* __restrict__ out_idx, int* __restrict__ idxbuf, float* __restrict__ counts)
{
  __shared__ float bv[256];
  __shared__ int bi[256];
  int nr = *rcnt;
  for (int e = blockIdx.x; e < nr; e += gridDim.x) {
    int r = rlist[e];
    const float* xr = X + (size_t)r * DIM;
    float best = 3.4e38f;
    int besti = 0;
    for (int c0 = 0; c0 < 8; ++c0) {
      int c = threadIdx.x * 8 + c0;   // ascending per thread
      const float* cp = C + (size_t)c * DIM;
      float acc = 0.f;
      for (int k = 0; k < DIM; k += 4) {
        float4 a = *(const float4*)(xr + k);
        float4 b = *(const float4*)(cp + k);
        acc += a.x * b.x + a.y * b.y + a.z * b.z + a.w * b.w;
      }
      float d = (sumsq[r] - 2.0f * acc) + csq[c];
      if (d < best) { best = d; besti = c; }
    }
    bv[threadIdx.x] = best; bi[threadIdx.x] = besti;
    __syncthreads();
    for (int s = 128; s > 0; s >>= 1) {
      if (threadIdx.x < s) {
        float ov = bv[threadIdx.x + s]; int oi = bi[threadIdx.x + s];
        if (ov < bv[threadIdx.x] || (ov == bv[threadIdx.x] && oi < bi[threadIdx.x])) {
          bv[threadIdx.x] = ov; bi[threadIdx.x] = oi;
        }
      }
      __syncthreads();
    }
    if (threadIdx.x == 0) {
      out_idx[r] = (float)bi[0];
      idxbuf[r] = bi[0];
      atomicAdd(&counts[bi[0]], 1.0f);
    }
    __syncthreads();
  }
}

// ============================================================================
//                     fp32 FALLBACK PATH (round-1 kernels)
// ============================================================================

__global__ __launch_bounds__(256) void vq_precompute(
    const float* __restrict__ X, const float* __restrict__ C,
    float* __restrict__ sumsq, float* __restrict__ csq, float* __restrict__ counts)
{
  int bid = blockIdx.x, tid = threadIdx.x;
  int wave = tid >> 6, lane = tid & 63;
  if (bid < 8192) {
    int row = bid * 4 + wave;
    float4 v = *(const float4*)(X + (size_t)row * DIM + lane * 4);
    float s = v.x * v.x + v.y * v.y + v.z * v.z + v.w * v.w;
#pragma unroll
    for (int off = 32; off > 0; off >>= 1) s += __shfl_down(s, off);
    if (lane == 0) sumsq[row] = s;
  } else if (bid < 8704) {
    int cent = (bid - 8192) * 4 + wave;
    float4 v = *(const float4*)(C + (size_t)cent * DIM + lane * 4);
    float s = v.x * v.x + v.y * v.y + v.z * v.z + v.w * v.w;
#pragma unroll
    for (int off = 32; off > 0; off >>= 1) s += __shfl_down(s, off);
    if (lane == 0) csq[cent] = s;
  } else {
    for (int i = tid; i < KCENT; i += 256) counts[i] = 0.0f;
  }
}

__global__ __launch_bounds__(256) void vq_argmin(
    const float* __restrict__ X, const float* __restrict__ C,
    const float* __restrict__ sumsq, const float* __restrict__ csq,
    float* __restrict__ pval, int* __restrict__ pidx)
{
  __shared__ __align__(16) float sA[BM * LSTR];
  __shared__ __align__(16) float sB[BN * LSTR];

  const int tid = threadIdx.x;
  const int tx = tid & 15, ty = tid >> 4;
  const int row0 = blockIdx.x * BM;
  const int g = blockIdx.y;
  const int cg0 = g * CPG;

  float sx[4];
#pragma unroll
  for (int m = 0; m < 4; ++m) sx[m] = sumsq[row0 + ty + 16 * m];

  float rmin[4];
  int ridx[4];
#pragma unroll
  for (int m = 0; m < 4; ++m) { rmin[m] = 3.4e38f; ridx[m] = 0; }

  for (int t = 0; t < CPG / BN; ++t) {
    const int c0 = cg0 + t * BN;
    float acc[4][4];
#pragma unroll
    for (int m = 0; m < 4; ++m)
#pragma unroll
      for (int n = 0; n < 4; ++n) acc[m][n] = 0.0f;

    for (int kc = 0; kc < DIM; kc += BKK) {
      __syncthreads();
#pragma unroll
      for (int s = 0; s < 2; ++s) {
        int id = tid + s * 256;
        int r = id >> 3;
        int c4 = (id & 7) << 2;
        float4 va = *(const float4*)(X + (size_t)(row0 + r) * DIM + kc + c4);
        *(float4*)&sA[r * LSTR + c4] = va;
        float4 vb = *(const float4*)(C + (size_t)(c0 + r) * DIM + kc + c4);
        *(float4*)&sB[r * LSTR + c4] = vb;
      }
      __syncthreads();
#pragma unroll
      for (int j = 0; j < BKK; j += 4) {
        float4 a[4], b[4];
#pragma unroll
        for (int m = 0; m < 4; ++m) a[m] = *(const float4*)&sA[(ty + 16 * m) * LSTR + j];
#pragma unroll
        for (int n = 0; n < 4; ++n) b[n] = *(const float4*)&sB[(tx + 16 * n) * LSTR + j];
#pragma unroll
        for (int m = 0; m < 4; ++m)
#pragma unroll
          for (int n = 0; n < 4; ++n)
            acc[m][n] += a[m].x * b[n].x + a[m].y * b[n].y + a[m].z * b[n].z + a[m].w * b[n].w;
      }
    }

#pragma unroll
    for (int m = 0; m < 4; ++m) {
#pragma unroll
      for (int n = 0; n < 4; ++n) {
        int cent = c0 + tx + 16 * n;
        float d = (sx[m] - 2.0f * acc[m][n]) + csq[cent];
        if (d < rmin[m]) { rmin[m] = d; ridx[m] = cent; }
      }
    }
  }

  __syncthreads();
  float* rv = sA;
  int* ri = (int*)sB;
#pragma unroll
  for (int m = 0; m < 4; ++m) {
    rv[(ty + 16 * m) * 16 + tx] = rmin[m];
    ri[(ty + 16 * m) * 16 + tx] = ridx[m];
  }
  __syncthreads();
  if (tid < 64) {
    float bvv = rv[tid * 16];
    int bii = ri[tid * 16];
#pragma unroll
    for (int t2 = 1; t2 < 16; ++t2) {
      float v = rv[tid * 16 + t2];
      int i = ri[tid * 16 + t2];
      if (v < bvv || (v == bvv && i < bii)) { bvv = v; bii = i; }
    }
    pval[g * N_ROWS + row0 + tid] = bvv;
    pidx[g * N_ROWS + row0 + tid] = bii;
  }
}

__global__ __launch_bounds__(256) void vq_reduce(
    const float* __restrict__ pval, const int* __restrict__ pidx,
    float* __restrict__ out_idx, int* __restrict__ idxbuf, float* __restrict__ counts)
{
  int r = blockIdx.x * 256 + threadIdx.x;
  float bv = pval[r];
  int bi = pidx[r];
#pragma unroll
  for (int g = 1; g < NSPLIT; ++g) {
    float v = pval[g * N_ROWS + r];
    int i = pidx[g * N_ROWS + r];
    if (v < bv || (v == bv && i < bi)) { bv = v; bi = i; }
  }
  out_idx[r] = (float)bi;
  idxbuf[r] = bi;
  atomicAdd(&counts[bi], 1.0f);
}

// ---------------- shared outputs kernel -------------------------------------
__global__ __launch_bounds__(256) void vq_outputs(
    const float* __restrict__ X, const float* __restrict__ C,
    const float* __restrict__ cc, const int* __restrict__ idxbuf,
    const float* __restrict__ counts, float* __restrict__ out)
{
  int bid = blockIdx.x, tid = threadIdx.x;
  if (bid < 8192) {
    int f4 = bid * 256 + tid;
    int row = f4 >> 6;
    int col = (f4 & 63) << 2;
    int idx = idxbuf[row];
    float4 x = *(const float4*)(X + (size_t)row * DIM + col);
    float4 q = *(const float4*)(C + (size_t)idx * DIM + col);
    float4 o, l;
    float dx = q.x - x.x, dy = q.y - x.y, dz = q.z - x.z, dw = q.w - x.w;
    o.x = x.x + dx; o.y = x.y + dy; o.z = x.z + dz; o.w = x.w + dw;
    float s0 = dx * dx, s1 = dy * dy, s2 = dz * dz, s3 = dw * dw;
    l.x = s0 + 0.25f * s0; l.y = s1 + 0.25f * s1;
    l.z = s2 + 0.25f * s2; l.w = s3 + 0.25f * s3;
    *(float4*)(out + OUT_Q + (size_t)f4 * 4) = o;
    *(float4*)(out + OUT_LOSS + (size_t)f4 * 4) = l;
  } else if (bid < 8704) {
    int f4 = (bid - 8192) * 256 + tid;
    float4 v = *(const float4*)(C + (size_t)f4 * 4);
    *(float4*)(out + OUT_CB + (size_t)f4 * 4) = v;
  } else {
    for (int i = tid; i < KCENT; i += 256)
      out[OUT_CNT + i] = 0.99f * cc[i] + 0.01f * counts[i];
  }
}

// ============================================================================
extern "C" void kernel_launch(void* const* d_in, const int* in_sizes, int n_in,
                              void* d_out, int out_size, void* d_ws, size_t ws_size,
                              hipStream_t stream) {
  const float* X = (const float*)d_in[0];
  const float* C = (const float*)d_in[1];
  const float* cc = (const float*)d_in[2];
  float* out = (float*)d_out;
  char* wsb = (char*)d_ws;

  if (ws_size >= WS_NEED) {
    // ---------------- MFMA path ----------------
    ushort_t* A2 = (ushort_t*)(wsb + WB_A2);
    ushort_t* B3 = (ushort_t*)(wsb + WB_B3);
    float* pv1 = (float*)(wsb + WB_PV1);
    int* pi1 = (int*)(wsb + WB_PI1);
    float* pv2 = (float*)(wsb + WB_PV2);
    float* sumsq = (float*)(wsb + WB_SUMSQ);
    float* xlo_n = (float*)(wsb + WB_XLO);
    float* xr_n = (float*)(wsb + WB_XR);
    float* csq = (float*)(wsb + WB_CSQ);
    float* counts = (float*)(wsb + WB_COUNTS);
    int* idxbuf = (int*)(wsb + WB_IDXBUF);
    int* rlist = (int*)(wsb + WB_RLIST);
    int* rcnt = (int*)(wsb + WB_MISC);
    unsigned* maxes = (unsigned*)(wsb + WB_MISC + 8);

    vq_init<<<1, 256, 0, stream>>>(counts, rcnt, maxes);
    vq_conv_x<<<N_ROWS / 4, 256, 0, stream>>>(X, A2, sumsq, xlo_n, xr_n);
    vq_conv_c<<<KCENT / 4, 256, 0, stream>>>(C, B3, csq, maxes);
    vq_mfma<<<dim3(KCENT / GBN, N_ROWS / GBM), 256, 0, stream>>>(
        A2, B3, sumsq, csq, pv1, pi1, pv2);
    vq_flagreduce<<<N_ROWS / 256, 256, 0, stream>>>(
        pv1, pi1, pv2, sumsq, xlo_n, xr_n, maxes,
        out + OUT_IDX, idxbuf, counts, rcnt, rlist);
    vq_rescue<<<64, 256, 0, stream>>>(X, C, sumsq, csq, rcnt, rlist,
                                      out + OUT_IDX, idxbuf, counts);
    vq_outputs<<<8705, 256, 0, stream>>>(X, C, cc, idxbuf, counts, out);
  } else {
    // ---------------- fp32 fallback (round-1) ----------------
    float* ws = (float*)d_ws;
    float* sumsq = ws + WS_SUMSQ;
    float* csq = ws + WS_CSQ;
    float* counts = ws + WS_COUNTS;
    int* idxbuf = (int*)(ws + WS_IDX);
    float* pval = ws + WS_PVAL;
    int* pidx = (int*)(ws + WS_PIDX);

    vq_precompute<<<8705, 256, 0, stream>>>(X, C, sumsq, csq, counts);
    vq_argmin<<<dim3(N_ROWS / BM, NSPLIT), 256, 0, stream>>>(X, C, sumsq, csq, pval, pidx);
    vq_reduce<<<N_ROWS / 256, 256, 0, stream>>>(pval, pidx, out + OUT_IDX, idxbuf, counts);
    vq_outputs<<<8705, 256, 0, stream>>>(X, C, cc, idxbuf, counts, out);
  }
}